// Round 17
// baseline (504.987 us; speedup 1.0000x reference)
//
#include <hip/hip_runtime.h>

typedef unsigned short u16;
typedef __attribute__((ext_vector_type(8))) short bf16x8;
typedef __attribute__((ext_vector_type(4))) float f32x4;

__device__ __forceinline__ float b2f(u16 h){ return __uint_as_float(((unsigned)h)<<16); }
__device__ __forceinline__ u16 f2b(float f){
  unsigned u = __float_as_uint(f);
  unsigned r = ((u>>16)&1u) + 0x7fffu;
  return (u16)((u+r)>>16);
}
__device__ __forceinline__ short4 pack4(float4 f){
  short4 s; s.x=(short)f2b(f.x); s.y=(short)f2b(f.y); s.z=(short)f2b(f.z); s.w=(short)f2b(f.w);
  return s;
}

// WB bf16 arena: s-path weights, [O][K] layout
#define WB0   0        // [128][384]
#define WB1   49152    // [128][160]
#define WB2   69632    // [128][160]
#define WBF0  90112    // [512][192]
#define WBF1  188416   // [128][576]
#define WB_TOTAL 262144

// WVb bf16 arena: v-path weights, [N_pad][K_pad]
#define V_WH0   0
#define V_WV0   7680
#define V_WH1   10752
#define V_WV1   11776
#define V_WH2   12800
#define V_WV2   13824
#define NV_FF0H 14848
#define NV_FF0V 16896
#define NV_FF1H 20992
#define NV_FF1V 25088
#define WV_TOTAL 27136

__global__ __launch_bounds__(256) void k_wb(const float* __restrict__ w0,
    const float* __restrict__ w1, const float* __restrict__ w2,
    const float* __restrict__ f0, const float* __restrict__ f1,
    u16* __restrict__ WB){
  int t = blockIdx.x*256 + threadIdx.x;
  if (t < 49152){
    int o = t/384, k = t - o*384;
    WB[WB0 + t] = f2b(k < 353 ? w0[(size_t)o*353 + k] : 0.f);
    return;
  }
  t -= 49152;
  if (t < 20480){ WB[WB1 + t] = f2b(w1[t]); return; }
  t -= 20480;
  if (t < 20480){ WB[WB2 + t] = f2b(w2[t]); return; }
  t -= 20480;
  if (t < 98304){ WB[WBF0 + t] = f2b(f0[t]); return; }
  t -= 98304;
  if (t < 73728){ WB[WBF1 + t] = f2b(f1[t]); return; }
}

__global__ __launch_bounds__(256) void k_wv(const float* __restrict__ wh0, const float* __restrict__ wv0,
    const float* __restrict__ wh1, const float* __restrict__ wv1,
    const float* __restrict__ wh2, const float* __restrict__ wv2,
    const float* __restrict__ nf0h, const float* __restrict__ nf0v,
    const float* __restrict__ nf1h, const float* __restrict__ nf1v,
    u16* __restrict__ WVb){
  int t = blockIdx.x*256 + threadIdx.x;
  if (t < 7680){
    int n=t/96, k=t-n*96;
    float v = 0.f;
    if (n < 65){
      if (k < 32)       v = wh0[(size_t)n*65 + k];
      else if (k < 64)  v = wh0[(size_t)n*65 + 33 + (k-32)];
      else if (k == 64) v = wh0[(size_t)n*65 + 32];
    }
    WVb[V_WH0+t] = f2b(v);
    return;
  }
  t -= 7680;
  if (t < 3072){
    int n=t/96, k=t-n*96;
    WVb[V_WV0+t] = f2b((k<65) ? wv0[(size_t)n*65+k] : 0.f);
    return;
  }
  t -= 3072;
  if (t < 1024){ WVb[V_WH1+t]=f2b(wh1[t]); return; }
  t -= 1024;
  if (t < 1024){ WVb[V_WV1+t]=f2b(wv1[t]); return; }
  t -= 1024;
  if (t < 1024){ WVb[V_WH2+t]=f2b(wh2[t]); return; }
  t -= 1024;
  if (t < 1024){ WVb[V_WV2+t]=f2b(wv2[t]); return; }
  t -= 1024;
  if (t < 2048){ WVb[NV_FF0H+t]=f2b(nf0h[t]); return; }
  t -= 2048;
  if (t < 4096){ WVb[NV_FF0V+t]=f2b(nf0v[t]); return; }
  t -= 4096;
  if (t < 4096){ WVb[NV_FF1H+t]=f2b(nf1h[t]); return; }
  t -= 4096;
  if (t < 2048){ WVb[NV_FF1V+t]=f2b(nf1v[t]); return; }
}

// prep: node_s -> bf16; node_v -> bf16 d-major; edge_s -> bf16 (linear)
__global__ __launch_bounds__(256) void k_prep(const float* __restrict__ node_s,
    const float* __restrict__ node_v, const float* __restrict__ edge_s,
    u16* __restrict__ node_sb, u16* __restrict__ node_vb, u16* __restrict__ esb_lin,
    int N, int E){
  int t = blockIdx.x*256 + threadIdx.x;
  if (t < N*128){ node_sb[t] = f2b(node_s[t]); return; }
  t -= N*128;
  if (t < N*96){
    int n=t/96, r=t-n*96, d=r>>5, vo=r&31;
    node_vb[(size_t)n*96 + d*32 + vo] = f2b(node_v[(size_t)n*96 + vo*3 + d]);
    return;
  }
  t -= N*96;
  if (t < E*32){ esb_lin[t] = f2b(edge_s[t]); return; }
}

__global__ __launch_bounds__(256) void k_hist(const int* __restrict__ ei, int E,
                                              float* __restrict__ cnt){
  int e = blockIdx.x*256 + threadIdx.x;
  if (e < E) atomicAdd(&cnt[ei[(size_t)E + e]], 1.f);
}

__global__ __launch_bounds__(256) void k_scan(const float* __restrict__ cnt,
                                              int* __restrict__ wpos, int N){
  __shared__ int part[256];
  const int tid = threadIdx.x;
  const int per = (N + 255)/256;
  const int base = tid*per;
  int s = 0;
  for (int i=0;i<per;++i){ int n=base+i; if (n<N) s += (int)cnt[n]; }
  part[tid] = s; __syncthreads();
  for (int st=1; st<256; st<<=1){
    int v = (tid>=st) ? part[tid-st] : 0;
    __syncthreads();
    part[tid] += v;
    __syncthreads();
  }
  int run = part[tid] - s;
  for (int i=0;i<per;++i){ int n=base+i; if (n<N){ wpos[n]=run; run += (int)cnt[n]; } }
}

__global__ __launch_bounds__(256) void k_scatter(const int* __restrict__ ei, int E,
                                                 int* __restrict__ wpos, int* __restrict__ perm){
  int e = blockIdx.x*256 + threadIdx.x;
  if (e >= E) return;
  int d = ei[(size_t)E + e];
  int pos = atomicAdd(&wpos[d], 1);
  perm[pos] = e;
}

// pre-gather edge features into dst-sorted bf16 arenas (bf16 source for es)
__global__ __launch_bounds__(256) void k_sortedge(
    const u16* __restrict__ esb_lin, const float* __restrict__ ev,
    const int* __restrict__ perm,
    u16* __restrict__ esb, u16* __restrict__ evb, int E)
{
  int t = blockIdx.x*256 + threadIdx.x;
  if (t >= E*9) return;
  int pos = t/9, p = t - pos*9;
  int e = perm[pos];
  if (p < 8){
    *(short4*)&esb[(size_t)pos*32 + 4*p] = *(const short4*)&esb_lin[(size_t)e*32 + 4*p];
  } else {
    evb[(size_t)pos*4+0] = f2b(ev[(size_t)e*3+0]);
    evb[(size_t)pos*4+1] = f2b(ev[(size_t)e*3+1]);
    evb[(size_t)pos*4+2] = f2b(ev[(size_t)e*3+2]);
    evb[(size_t)pos*4+3] = 0;
  }
}

// ---------- fused edge kernel: v-path + s-path, T14 prefetch, parallel seg-reduce ----------
#define EPB 32
__global__ __launch_bounds__(512) void k_edge_fused(
    const u16* __restrict__ node_sb, const u16* __restrict__ node_vb,
    const u16* __restrict__ esb, const u16* __restrict__ evb,
    const int* __restrict__ ei, int E, const int* __restrict__ perm,
    const u16* __restrict__ WB, const u16* __restrict__ WVb,
    const float* __restrict__ b0p, const float* __restrict__ b1p, const float* __restrict__ b2p,
    float* __restrict__ agg_s, float* __restrict__ agg_v)
{
  __shared__ __align__(16) char R1[42240];
  __shared__ __align__(16) u16 VN0[EPB][80];
  __shared__ __align__(16) u16 VN1[EPB][32];
  __shared__ __align__(16) u16 VN2[EPB][32];
  __shared__ int SD[EPB][2];
  u16 (*B0)[104]  = (u16(*)[104])R1;
  u16 (*B1)[104]  = (u16(*)[104])(R1 + 20480);
  float (*SCv)[33] = (float(*)[33])R1;
  u16 (*A)[392]   = (u16(*)[392])R1;
  float (*SC)[132] = (float(*)[132])R1;

  const int tid = threadIdx.x;
  const int w = tid>>6, l = tid&63;
  const int le0 = blockIdx.x*EPB;

  if (tid < EPB){
    int le = le0 + tid;
    int ge = (le<E) ? perm[le] : 0;
    SD[tid][0] = ei[ge];
    SD[tid][1] = ei[(size_t)E + ge];
  }
  __syncthreads();

  // T14 prefetch: issue s-path gathers into registers NOW; LDS-write after v-path.
  short4 pre0={0,0,0,0}, pre1={0,0,0,0}, pre2={0,0,0,0}, pre3={0,0,0,0}, pre4={0,0,0,0};
  {
    auto ld = [&](int u)->short4{
      short4 v = {0,0,0,0};
      if (u < EPB*72){
        int ee = u/72, g = u - ee*72;
        int le = le0+ee;
        if (le<E){
          if (g < 32)      v = *(const short4*)&node_sb[(size_t)SD[ee][0]*128 + 4*g];
          else if (g < 40) v = *(const short4*)&esb[(size_t)le*32 + 4*(g-32)];
          else             v = *(const short4*)&node_sb[(size_t)SD[ee][1]*128 + 4*(g-40)];
        }
      }
      return v;
    };
    pre0 = ld(tid);          pre1 = ld(tid + 512);
    pre2 = ld(tid + 1024);   pre3 = ld(tid + 1536);
    pre4 = ld(tid + 2048);
  }

  // v-path staging
  for (int u=tid; u<96*16; u+=512){
    int r=u>>4, g=u&15, ee=r/3, d=r-ee*3;
    int le=le0+ee;
    short4 v = {0,0,0,0};
    if (le<E){
      int node = (g<8) ? SD[ee][0] : SD[ee][1];
      v = *(const short4*)&node_vb[(size_t)node*96 + d*32 + 4*(g&7)];
    }
    *(short4*)&B0[r][4*g] = v;
  }
  for (int u=tid; u<96*8; u+=512){
    int r=u>>3, g=u&7, ee=r/3, d=r-ee*3;
    int le=le0+ee;
    short4 v = {0,0,0,0};
    if (g==0 && le<E) v.x = (short)evb[(size_t)le*4 + d];
    *(short4*)&B0[r][64+4*g] = v;
  }
  for (int u=tid; u<96*4; u+=512){
    int r=u>>2, g=u&3;
    *(short4*)&B1[r][80+4*g] = (short4){0,0,0,0};
  }
  __syncthreads();

  auto mm = [&](const u16 (*Ai)[104], int woff, int Kp, int NT, u16 (*C)[104]){
    const int nks = Kp>>5;
    for (int t=w; t<6*NT; t+=8){
      int mt = t % 6, nt = t / 6;
      f32x4 acc = {0.f,0.f,0.f,0.f};
      for (int ks=0; ks<nks; ++ks){
        bf16x8 af = *(const bf16x8*)&Ai[mt*16 + (l&15)][ks*32 + (l>>4)*8];
        bf16x8 bf = *(const bf16x8*)&WVb[woff + (size_t)(nt*16 + (l&15))*Kp + ks*32 + (l>>4)*8];
        acc = __builtin_amdgcn_mfma_f32_16x16x32_bf16(af, bf, acc, 0, 0, 0);
      }
      const int col = nt*16 + (l&15);
      const int r0 = mt*16 + (l>>4)*4;
      C[r0+0][col]=f2b(acc[0]); C[r0+1][col]=f2b(acc[1]);
      C[r0+2][col]=f2b(acc[2]); C[r0+3][col]=f2b(acc[3]);
    }
  };

  // ---- v-path ----
  mm(B0, V_WH0, 96, 5, B1);
  __syncthreads();
  for (int u=tid; u<EPB*80; u+=512){
    int ee=u/80, h=u-ee*80;
    u16 val = 0;
    if (h<65){
      float x0=b2f(B1[ee*3+0][h]), x1=b2f(B1[ee*3+1][h]), x2=b2f(B1[ee*3+2][h]);
      val = f2b(sqrtf(fmaxf(x0*x0+x1*x1+x2*x2, 1e-8f)));
    }
    VN0[ee][h] = val;
  }
  mm(B1, V_WV0, 96, 2, B0);
  __syncthreads();
  for (int u=tid; u<EPB*32; u+=512){
    int ee=u>>5, vo=u&31;
    float x0=b2f(B0[ee*3+0][vo]), x1=b2f(B0[ee*3+1][vo]), x2=b2f(B0[ee*3+2][vo]);
    float nn=sqrtf(fmaxf(x0*x0+x1*x1+x2*x2, 1e-8f));
    float sg=1.f/(1.f+__expf(-nn));
    B0[ee*3+0][vo]=f2b(x0*sg); B0[ee*3+1][vo]=f2b(x1*sg); B0[ee*3+2][vo]=f2b(x2*sg);
  }
  __syncthreads();
  mm(B0, V_WH1, 32, 2, B1);
  __syncthreads();
  for (int u=tid; u<EPB*32; u+=512){
    int ee=u>>5, h=u&31;
    float x0=b2f(B1[ee*3+0][h]), x1=b2f(B1[ee*3+1][h]), x2=b2f(B1[ee*3+2][h]);
    VN1[ee][h] = f2b(sqrtf(fmaxf(x0*x0+x1*x1+x2*x2, 1e-8f)));
  }
  mm(B1, V_WV1, 32, 2, B0);
  __syncthreads();
  for (int u=tid; u<EPB*32; u+=512){
    int ee=u>>5, vo=u&31;
    float x0=b2f(B0[ee*3+0][vo]), x1=b2f(B0[ee*3+1][vo]), x2=b2f(B0[ee*3+2][vo]);
    float nn=sqrtf(fmaxf(x0*x0+x1*x1+x2*x2, 1e-8f));
    float sg=1.f/(1.f+__expf(-nn));
    B0[ee*3+0][vo]=f2b(x0*sg); B0[ee*3+1][vo]=f2b(x1*sg); B0[ee*3+2][vo]=f2b(x2*sg);
  }
  __syncthreads();
  mm(B0, V_WH2, 32, 2, B1);
  __syncthreads();
  for (int u=tid; u<EPB*32; u+=512){
    int ee=u>>5, h=u&31;
    float x0=b2f(B1[ee*3+0][h]), x1=b2f(B1[ee*3+1][h]), x2=b2f(B1[ee*3+2][h]);
    VN2[ee][h] = f2b(sqrtf(fmaxf(x0*x0+x1*x1+x2*x2, 1e-8f)));
  }
  for (int t=w; t<12; t+=8){
    int mt = t % 6, nt = t / 6;
    f32x4 acc = {0.f,0.f,0.f,0.f};
    bf16x8 af = *(const bf16x8*)&B1[mt*16 + (l&15)][(l>>4)*8];
    bf16x8 bf = *(const bf16x8*)&WVb[V_WV2 + (size_t)(nt*16 + (l&15))*32 + (l>>4)*8];
    acc = __builtin_amdgcn_mfma_f32_16x16x32_bf16(af, bf, acc, 0, 0, 0);
    const int vo = nt*16 + (l&15);
    const int r0 = mt*16 + (l>>4)*4;
    #pragma unroll
    for (int j=0;j<4;++j){
      int r = r0 + j;
      int le = le0 + r/3;
      SCv[r][vo] = (le < E) ? acc[j] : 0.f;
    }
  }
  __syncthreads();
  if (tid < 384){
    const int part = tid / 96, vd = tid - part*96;
    const int vo = vd & 31, d = vd >> 5;
    float run = 0.f; int prev = -1;
    for (int ee=part*8; ee<part*8+8; ++ee){
      int le = le0 + ee;
      int dn = (le<E) ? SD[ee][1] : -1;
      if (dn != prev){
        if (prev >= 0) atomicAdd(&agg_v[(size_t)prev*96 + vo*3 + d], run);
        run = 0.f; prev = dn;
      }
      run += SCv[ee*3+d][vo];
    }
    if (prev >= 0) atomicAdd(&agg_v[(size_t)prev*96 + vo*3 + d], run);
  }
  __syncthreads();

  // ---- s-path staging: write prefetched registers + VN0 ----
  {
    auto st = [&](int u, short4 v){
      if (u < EPB*72){
        int ee = u/72, g = u - ee*72;
        *(short4*)&A[ee][4*g] = v;
      }
    };
    st(tid, pre0); st(tid+512, pre1); st(tid+1024, pre2); st(tid+1536, pre3); st(tid+2048, pre4);
  }
  for (int u=tid; u<EPB*26; u+=512){
    int ee = u/26, g = 72 + (u - ee*26);
    short4 v = {0,0,0,0};
    if (g < 92) v = *(const short4*)&VN0[ee][4*(g-72)];
    *(short4*)&A[ee][4*g] = v;
  }
  __syncthreads();

  const int mt = w>>2, nt = w&3;
  const int n_a = nt*32 + (l&15), n_b = n_a + 16;
  const int kq = (l>>4)*8;
  const int ma = mt*16 + (l&15);
  f32x4 ca = {0.f,0.f,0.f,0.f}, cb = {0.f,0.f,0.f,0.f};

  for (int kk=0; kk<384; kk+=32){
    bf16x8 af = *(const bf16x8*)&A[ma][kk + kq];
    bf16x8 b1 = *(const bf16x8*)&WB[WB0 + (size_t)n_a*384 + kk + kq];
    bf16x8 b2 = *(const bf16x8*)&WB[WB0 + (size_t)n_b*384 + kk + kq];
    ca = __builtin_amdgcn_mfma_f32_16x16x32_bf16(af, b1, ca, 0, 0, 0);
    cb = __builtin_amdgcn_mfma_f32_16x16x32_bf16(af, b2, cb, 0, 0, 0);
  }
  __syncthreads();
  {
    float ba = b0p[n_a], bb = b0p[n_b];
    #pragma unroll
    for (int j=0;j<4;++j){
      int r = mt*16 + (l>>4)*4 + j;
      A[r][n_a] = f2b(fmaxf(ca[j] + ba, 0.f));
      A[r][n_b] = f2b(fmaxf(cb[j] + bb, 0.f));
    }
  }
  for (int u=tid; u<EPB*8; u+=512){
    int ee=u>>3, q=u&7;
    *(short4*)&A[ee][128+4*q] = *(const short4*)&VN1[ee][4*q];
  }
  __syncthreads();

  ca = (f32x4){0.f,0.f,0.f,0.f}; cb = (f32x4){0.f,0.f,0.f,0.f};
  for (int kk=0; kk<160; kk+=32){
    bf16x8 af = *(const bf16x8*)&A[ma][kk + kq];
    bf16x8 b1 = *(const bf16x8*)&WB[WB1 + (size_t)n_a*160 + kk + kq];
    bf16x8 b2 = *(const bf16x8*)&WB[WB1 + (size_t)n_b*160 + kk + kq];
    ca = __builtin_amdgcn_mfma_f32_16x16x32_bf16(af, b1, ca, 0, 0, 0);
    cb = __builtin_amdgcn_mfma_f32_16x16x32_bf16(af, b2, cb, 0, 0, 0);
  }
  __syncthreads();
  {
    float ba = b1p[n_a], bb = b1p[n_b];
    #pragma unroll
    for (int j=0;j<4;++j){
      int r = mt*16 + (l>>4)*4 + j;
      A[r][n_a] = f2b(fmaxf(ca[j] + ba, 0.f));
      A[r][n_b] = f2b(fmaxf(cb[j] + bb, 0.f));
    }
  }
  for (int u=tid; u<EPB*8; u+=512){
    int ee=u>>3, q=u&7;
    *(short4*)&A[ee][128+4*q] = *(const short4*)&VN2[ee][4*q];
  }
  __syncthreads();

  ca = (f32x4){0.f,0.f,0.f,0.f}; cb = (f32x4){0.f,0.f,0.f,0.f};
  for (int kk=0; kk<160; kk+=32){
    bf16x8 af = *(const bf16x8*)&A[ma][kk + kq];
    bf16x8 b1 = *(const bf16x8*)&WB[WB2 + (size_t)n_a*160 + kk + kq];
    bf16x8 b2 = *(const bf16x8*)&WB[WB2 + (size_t)n_b*160 + kk + kq];
    ca = __builtin_amdgcn_mfma_f32_16x16x32_bf16(af, b1, ca, 0, 0, 0);
    cb = __builtin_amdgcn_mfma_f32_16x16x32_bf16(af, b2, cb, 0, 0, 0);
  }
  __syncthreads();
  {
    float ba = b2p[n_a], bb = b2p[n_b];
    #pragma unroll
    for (int j=0;j<4;++j){
      int r = mt*16 + (l>>4)*4 + j;
      int le = le0 + r;
      SC[r][n_a] = (le<E) ? (ca[j] + ba) : 0.f;
      SC[r][n_b] = (le<E) ? (cb[j] + bb) : 0.f;
    }
  }
  __syncthreads();
  {
    const int part = tid >> 7, c = tid & 127;
    float run = 0.f; int prev = -1;
    for (int r=part*8; r<part*8+8; ++r){
      int le = le0 + r;
      int dn = (le<E) ? SD[r][1] : -1;
      if (dn != prev){
        if (prev >= 0) atomicAdd(&agg_s[(size_t)prev*128 + c], run);
        run = 0.f; prev = dn;
      }
      run += SC[r][c];
    }
    if (prev >= 0) atomicAdd(&agg_s[(size_t)prev*128 + c], run);
  }
}

// ---------- residual + tuple LayerNorm: 64 nodes/block, 4 threads/node ----------
__global__ __launch_bounds__(256) void k_ln0(
    const float* __restrict__ node_s, const float* __restrict__ node_v,
    const float* __restrict__ agg_s, const float* __restrict__ agg_v,
    const float* __restrict__ cnt,
    const float* __restrict__ g, const float* __restrict__ b,
    float* __restrict__ s_mid, float* __restrict__ v_mid, int N)
{
  const int tid = threadIdx.x, q = tid&3;
  const int n = blockIdx.x*64 + (tid>>2);
  const bool live = n < N;
  const float inv = live ? 1.f/fmaxf(cnt[n], 1.f) : 1.f;
  float xs[32];
  float sum=0.f, ss=0.f;
  if (live){
    #pragma unroll
    for (int j=0;j<8;++j){
      float4 a = *(const float4*)&node_s[(size_t)n*128 + q*32 + 4*j];
      float4 c = *(const float4*)&agg_s[(size_t)n*128 + q*32 + 4*j];
      xs[4*j+0]=a.x+c.x*inv; xs[4*j+1]=a.y+c.y*inv; xs[4*j+2]=a.z+c.z*inv; xs[4*j+3]=a.w+c.w*inv;
      sum += xs[4*j+0]+xs[4*j+1]+xs[4*j+2]+xs[4*j+3];
      ss  += xs[4*j+0]*xs[4*j+0]+xs[4*j+1]*xs[4*j+1]+xs[4*j+2]*xs[4*j+2]+xs[4*j+3]*xs[4*j+3];
    }
  }
  sum += __shfl_xor(sum,1); sum += __shfl_xor(sum,2);
  ss  += __shfl_xor(ss,1);  ss  += __shfl_xor(ss,2);
  const float mu = sum*(1.f/128.f);
  const float var = fmaxf(ss*(1.f/128.f) - mu*mu, 0.f);
  const float rstd = rsqrtf(var + 1e-5f);
  if (live){
    #pragma unroll
    for (int j=0;j<8;++j){
      float4 gg = *(const float4*)&g[q*32 + 4*j];
      float4 bb = *(const float4*)&b[q*32 + 4*j];
      float4 o;
      o.x=(xs[4*j+0]-mu)*rstd*gg.x+bb.x; o.y=(xs[4*j+1]-mu)*rstd*gg.y+bb.y;
      o.z=(xs[4*j+2]-mu)*rstd*gg.z+bb.z; o.w=(xs[4*j+3]-mu)*rstd*gg.w+bb.w;
      *(float4*)&s_mid[(size_t)n*128 + q*32 + 4*j] = o;
    }
  }
  float yv[24]; float vs=0.f;
  if (live){
    #pragma unroll
    for (int j=0;j<6;++j){
      float4 a = *(const float4*)&node_v[(size_t)n*96 + q*24 + 4*j];
      float4 c = *(const float4*)&agg_v[(size_t)n*96 + q*24 + 4*j];
      yv[4*j+0]=a.x+c.x*inv; yv[4*j+1]=a.y+c.y*inv; yv[4*j+2]=a.z+c.z*inv; yv[4*j+3]=a.w+c.w*inv;
    }
    #pragma unroll
    for (int vv=0; vv<8; ++vv){
      float z0=yv[3*vv], z1=yv[3*vv+1], z2=yv[3*vv+2];
      vs += fmaxf(z0*z0+z1*z1+z2*z2, 1e-8f);
    }
  }
  vs += __shfl_xor(vs,1); vs += __shfl_xor(vs,2);
  const float scale = rsqrtf(vs*(1.f/32.f));
  if (live){
    #pragma unroll
    for (int vv=0; vv<8; ++vv){
      int vo = q*8 + vv;
      v_mid[(size_t)n*96 + vo]      = yv[3*vv]*scale;
      v_mid[(size_t)n*96 + 32 + vo] = yv[3*vv+1]*scale;
      v_mid[(size_t)n*96 + 64 + vo] = yv[3*vv+2]*scale;
    }
  }
}

// ---------- node vector FF (batched MFMA) ----------
__global__ __launch_bounds__(256) void k_node_v(
    const float* __restrict__ v_mid, const u16* __restrict__ WVb,
    u16* __restrict__ vn0f, u16* __restrict__ vn1f, float* __restrict__ fv1, int N)
{
  __shared__ __align__(16) u16 B0[96][104];
  __shared__ __align__(16) u16 B1[96][104];
  const int tid = threadIdx.x;
  const int w = tid>>6, l = tid&63;
  const int n0 = blockIdx.x*32;

  for (int u=tid; u<96*8; u+=256){
    int r=u>>3, g=u&7, nd=r/3, d=r-nd*3;
    int n=n0+nd;
    short4 v = {0,0,0,0};
    if (n<N) v = pack4(*(const float4*)&v_mid[(size_t)n*96 + d*32 + 4*g]);
    *(short4*)&B0[r][4*g] = v;
  }
  __syncthreads();

  auto mm = [&](const u16 (*A)[104], int woff, int Kp, int NT, u16 (*C)[104]){
    const int nks = Kp>>5;
    for (int t=w; t<6*NT; t+=4){
      int mt = t % 6, nt = t / 6;
      f32x4 acc = {0.f,0.f,0.f,0.f};
      for (int ks=0; ks<nks; ++ks){
        bf16x8 af = *(const bf16x8*)&A[mt*16 + (l&15)][ks*32 + (l>>4)*8];
        bf16x8 bf = *(const bf16x8*)&WVb[woff + (size_t)(nt*16 + (l&15))*Kp + ks*32 + (l>>4)*8];
        acc = __builtin_amdgcn_mfma_f32_16x16x32_bf16(af, bf, acc, 0, 0, 0);
      }
      const int col = nt*16 + (l&15);
      const int r0 = mt*16 + (l>>4)*4;
      C[r0+0][col]=f2b(acc[0]); C[r0+1][col]=f2b(acc[1]);
      C[r0+2][col]=f2b(acc[2]); C[r0+3][col]=f2b(acc[3]);
    }
  };

  mm(B0, NV_FF0H, 32, 4, B1);
  __syncthreads();
  for (int u=tid; u<32*64; u+=256){
    int nd=u>>6, h=u&63;
    int n=n0+nd;
    if (n<N){
      float x0=b2f(B1[nd*3+0][h]), x1=b2f(B1[nd*3+1][h]), x2=b2f(B1[nd*3+2][h]);
      vn0f[(size_t)n*64+h] = f2b(sqrtf(fmaxf(x0*x0+x1*x1+x2*x2, 1e-8f)));
    }
  }
  mm(B1, NV_FF0V, 64, 4, B0);
  __syncthreads();
  for (int u=tid; u<32*64; u+=256){
    int nd=u>>6, vo=u&63;
    float x0=b2f(B0[nd*3+0][vo]), x1=b2f(B0[nd*3+1][vo]), x2=b2f(B0[nd*3+2][vo]);
    float nn=sqrtf(fmaxf(x0*x0+x1*x1+x2*x2, 1e-8f));
    float sg=1.f/(1.f+__expf(-nn));
    B0[nd*3+0][vo]=f2b(x0*sg); B0[nd*3+1][vo]=f2b(x1*sg); B0[nd*3+2][vo]=f2b(x2*sg);
  }
  __syncthreads();
  mm(B0, NV_FF1H, 64, 4, B1);
  __syncthreads();
  for (int u=tid; u<32*64; u+=256){
    int nd=u>>6, h=u&63;
    int n=n0+nd;
    if (n<N){
      float x0=b2f(B1[nd*3+0][h]), x1=b2f(B1[nd*3+1][h]), x2=b2f(B1[nd*3+2][h]);
      vn1f[(size_t)n*64+h] = f2b(sqrtf(fmaxf(x0*x0+x1*x1+x2*x2, 1e-8f)));
    }
  }
  for (int t=w; t<12; t+=4){
    int mt = t % 6, nt = t / 6;
    f32x4 acc = {0.f,0.f,0.f,0.f};
    for (int ks=0; ks<2; ++ks){
      bf16x8 af = *(const bf16x8*)&B1[mt*16 + (l&15)][ks*32 + (l>>4)*8];
      bf16x8 bf = *(const bf16x8*)&WVb[NV_FF1V + (size_t)(nt*16 + (l&15))*64 + ks*32 + (l>>4)*8];
      acc = __builtin_amdgcn_mfma_f32_16x16x32_bf16(af, bf, acc, 0, 0, 0);
    }
    const int vo = nt*16 + (l&15);
    const int r0 = mt*16 + (l>>4)*4;
    #pragma unroll
    for (int j=0;j<4;++j){
      int r = r0 + j;
      int nd = r/3, d = r - nd*3;
      int n = n0 + nd;
      if (n < N) fv1[(size_t)n*96 + d*32 + vo] = acc[j];
    }
  }
}

// ---------- node scalar FF (2 MFMA GEMMs) + fused final LN -> d_out ----------
__global__ __launch_bounds__(512) void k_node_s(
    const float* __restrict__ s_mid, const u16* __restrict__ vn0f, const u16* __restrict__ vn1f,
    const float* __restrict__ v_mid, const float* __restrict__ fv1,
    const u16* __restrict__ WB,
    const float* __restrict__ fb0, const float* __restrict__ fb1,
    const float* __restrict__ ln1g, const float* __restrict__ ln1b,
    float* __restrict__ out, int N)
{
  __shared__ __align__(16) char U1[16896];
  __shared__ __align__(16) u16 A2[32][584];
  u16 (*A1)[200] = (u16(*)[200])U1;
  float (*FS)[132] = (float(*)[132])U1;
  const int tid = threadIdx.x;
  const int n0 = blockIdx.x*32;

  for (int u=tid; u<32*48; u+=512){
    int nd = u/48, g = u - nd*48;
    int n = n0+nd;
    short4 v = {0,0,0,0};
    if (n<N){
      if (g < 32) v = pack4(*(const float4*)&s_mid[(size_t)n*128 + 4*g]);
      else        v = *(const short4*)&vn0f[(size_t)n*64 + 4*(g-32)];
    }
    *(short4*)&A1[nd][4*g] = v;
  }
  __syncthreads();

  const int w = tid>>6, l = tid&63;
  const int mt = w>>2, ng = w&3;
  const int kq = (l>>4)*8;
  const int ma = mt*16 + (l&15);
  const int r0 = mt*16 + (l>>4)*4;

  for (int nt2=0; nt2<8; ++nt2){
    const int nt = ng*8 + nt2;
    const int col = nt*16 + (l&15);
    f32x4 acc = {0.f,0.f,0.f,0.f};
    for (int ks=0; ks<6; ++ks){
      bf16x8 af = *(const bf16x8*)&A1[ma][ks*32 + kq];
      bf16x8 bf = *(const bf16x8*)&WB[WBF0 + (size_t)col*192 + ks*32 + kq];
      acc = __builtin_amdgcn_mfma_f32_16x16x32_bf16(af, bf, acc, 0, 0, 0);
    }
    float bias = fb0[col];
    #pragma unroll
    for (int j=0;j<4;++j) A2[r0+j][col] = f2b(fmaxf(acc[j] + bias, 0.f));
  }
  __syncthreads();
  for (int u=tid; u<32*16; u+=512){
    int nd=u>>4, q=u&15;
    int n=n0+nd;
    short4 v = {0,0,0,0};
    if (n<N) v = *(const short4*)&vn1f[(size_t)n*64 + 4*q];
    *(short4*)&A2[nd][512+4*q] = v;
  }
  __syncthreads();

  for (int nt2=0; nt2<2; ++nt2){
    const int nt = ng*2 + nt2;
    const int col = nt*16 + (l&15);
    f32x4 acc = {0.f,0.f,0.f,0.f};
    for (int ks=0; ks<18; ++ks){
      bf16x8 af = *(const bf16x8*)&A2[ma][ks*32 + kq];
      bf16x8 bf = *(const bf16x8*)&WB[WBF1 + (size_t)col*576 + ks*32 + kq];
      acc = __builtin_amdgcn_mfma_f32_16x16x32_bf16(af, bf, acc, 0, 0, 0);
    }
    float bias = fb1[col];
    #pragma unroll
    for (int j=0;j<4;++j) FS[r0+j][col] = acc[j] + bias;
  }
  __syncthreads();

  {
    const int nd = tid>>4, q = tid&15;
    const int n = n0 + nd;
    const bool live = n < N;
    float xs[8], sum=0.f, ss=0.f;
    #pragma unroll
    for (int j=0;j<8;++j){
      int c = q*8 + j;
      float x = 0.f;
      if (live) x = s_mid[(size_t)n*128 + c] + FS[nd][c];
      xs[j] = x; sum += x; ss += x*x;
    }
    #pragma unroll
    for (int m=1; m<16; m<<=1){ sum += __shfl_xor(sum, m); ss += __shfl_xor(ss, m); }
    const float mu = sum*(1.f/128.f);
    const float var = fmaxf(ss*(1.f/128.f) - mu*mu, 0.f);
    const float rstd = rsqrtf(var + 1e-5f);
    if (live){
      #pragma unroll
      for (int j=0;j<8;++j){
        int c = q*8 + j;
        out[(size_t)n*128 + c] = (xs[j]-mu)*rstd*ln1g[c] + ln1b[c];
      }
    }
    float z[2][3]; float vs = 0.f;
    #pragma unroll
    for (int j=0;j<2;++j){
      int vo = q + 16*j;
      #pragma unroll
      for (int d=0;d<3;++d){
        float y = live ? (v_mid[(size_t)n*96 + d*32 + vo] + fv1[(size_t)n*96 + d*32 + vo]) : 0.f;
        z[j][d] = y;
      }
      vs += fmaxf(z[j][0]*z[j][0]+z[j][1]*z[j][1]+z[j][2]*z[j][2], 1e-8f);
    }
    #pragma unroll
    for (int m=1; m<16; m<<=1) vs += __shfl_xor(vs, m);
    const float scale = rsqrtf(vs*(1.f/32.f));
    if (live){
      size_t base = (size_t)N*128 + (size_t)n*96;
      #pragma unroll
      for (int j=0;j<2;++j){
        int vo = q + 16*j;
        out[base + vo*3 + 0] = z[j][0]*scale;
        out[base + vo*3 + 1] = z[j][1]*scale;
        out[base + vo*3 + 2] = z[j][2]*scale;
      }
    }
  }
}

extern "C" void kernel_launch(void* const* d_in, const int* in_sizes, int n_in,
                              void* d_out, int out_size, void* d_ws, size_t ws_size,
                              hipStream_t stream)
{
  (void)n_in; (void)out_size; (void)ws_size;
  const int N = in_sizes[0]/128;
  const int E = in_sizes[4]/2;
  const int* ei = (const int*)d_in[4];

  size_t off = 0;
  auto alloc = [&](size_t bytes)->char*{
    size_t o = (off + 255) & ~(size_t)255;
    off = o + bytes;
    return (char*)d_ws + o;
  };
  u16*   WB      = (u16*)alloc((size_t)WB_TOTAL*2);
  u16*   WVb     = (u16*)alloc((size_t)WV_TOTAL*2);
  float* agg_s   = (float*)alloc((size_t)N*128*4);
  float* agg_v   = (float*)alloc((size_t)N*96*4);
  float* cnt     = (float*)alloc((size_t)N*4);
  size_t aggBytes = (size_t)((char*)(cnt+N) - (char*)agg_s);
  float* s_mid   = (float*)alloc((size_t)N*128*4);
  float* v_mid   = (float*)alloc((size_t)N*96*4);
  u16*   node_sb = (u16*)alloc((size_t)N*128*2);
  u16*   node_vb = (u16*)alloc((size_t)N*96*2);
  u16*   vn0f    = (u16*)alloc((size_t)N*64*2);
  u16*   vn1f    = (u16*)alloc((size_t)N*64*2);
  float* fv1     = (float*)alloc((size_t)N*96*4);
  int*   wpos    = (int*)alloc((size_t)N*4);
  int*   perm    = (int*)alloc((size_t)E*4);
  u16*   esb_lin = (u16*)alloc((size_t)E*32*2);
  u16*   esb     = (u16*)alloc((size_t)E*32*2);
  u16*   evb     = (u16*)alloc((size_t)E*4*2);

  hipMemsetAsync(agg_s, 0, aggBytes, stream);
  k_wb<<<dim3((WB_TOTAL+255)/256), dim3(256), 0, stream>>>(
      (const float*)d_in[6], (const float*)d_in[10], (const float*)d_in[14],
      (const float*)d_in[20], (const float*)d_in[24], WB);
  k_wv<<<dim3((WV_TOTAL+255)/256), dim3(256), 0, stream>>>(
      (const float*)d_in[5], (const float*)d_in[8], (const float*)d_in[9],
      (const float*)d_in[12], (const float*)d_in[13], (const float*)d_in[16],
      (const float*)d_in[19], (const float*)d_in[22], (const float*)d_in[23],
      (const float*)d_in[26], WVb);
  k_prep<<<dim3(((size_t)N*224 + (size_t)E*32 + 255)/256), dim3(256), 0, stream>>>(
      (const float*)d_in[0], (const float*)d_in[1], (const float*)d_in[2],
      node_sb, node_vb, esb_lin, N, E);
  k_hist<<<dim3((E+255)/256), dim3(256), 0, stream>>>(ei, E, cnt);
  k_scan<<<dim3(1), dim3(256), 0, stream>>>(cnt, wpos, N);
  k_scatter<<<dim3((E+255)/256), dim3(256), 0, stream>>>(ei, E, wpos, perm);
  k_sortedge<<<dim3(((size_t)E*9+255)/256), dim3(256), 0, stream>>>(
      esb_lin, (const float*)d_in[3], perm, esb, evb, E);

  k_edge_fused<<<dim3((E+EPB-1)/EPB), dim3(512), 0, stream>>>(
      node_sb, node_vb, esb, evb, ei, E, perm, WB, WVb,
      (const float*)d_in[7], (const float*)d_in[11], (const float*)d_in[15],
      agg_s, agg_v);

  k_ln0<<<dim3((N+63)/64), dim3(256), 0, stream>>>(
      (const float*)d_in[0], (const float*)d_in[1], agg_s, agg_v, cnt,
      (const float*)d_in[17], (const float*)d_in[18], s_mid, v_mid, N);

  k_node_v<<<dim3((N+31)/32), dim3(256), 0, stream>>>(v_mid, WVb, vn0f, vn1f, fv1, N);
  k_node_s<<<dim3((N+31)/32), dim3(512), 0, stream>>>(
      s_mid, vn0f, vn1f, v_mid, fv1, WB,
      (const float*)d_in[21], (const float*)d_in[25],
      (const float*)d_in[27], (const float*)d_in[28],
      (float*)d_out, N);
}